// Round 15
// baseline (247.414 us; speedup 1.0000x reference)
//
#include <hip/hip_runtime.h>

#define N_NODES 100000
#define N_EDGES 1600000
#define NFEAT 256
#define NHID 128
#define NCLASS 40

#define NGROUP 8               // src ranges (key minor dim)
#define NODES_PER_GROUP 12500
#define NBKT 128               // dst buckets
#define NPB 782                // ceil(N_NODES / NBKT)
#define KPB (NPB * 8)          // 6256 keys per bucket
#define BCAP2 13200            // per-bucket capacity (mean 12500, +6.3 sigma)
#define EPB2 8192              // edges per fatA block (512 thr x 16)
#define NCH2 ((N_EDGES + EPB2 - 1) / EPB2)  // 196
#define NGEMM1 ((N_NODES + 127) / 128)  // 782
#define NKEY (N_NODES * 8)     // 800000 (dst*8 + src_range)

using short8 = __attribute__((ext_vector_type(8))) short;
using f32x4 = __attribute__((ext_vector_type(4))) float;
using i32x4 = __attribute__((ext_vector_type(4))) int;
using i32x2 = __attribute__((ext_vector_type(2))) int;

// ---------- bf16 helpers ----------
__device__ inline float blo(unsigned u) { return __uint_as_float(u << 16); }
__device__ inline float bhi(unsigned u) { return __uint_as_float(u & 0xffff0000u); }
__device__ inline unsigned pk2(float a, float b) {  // 2xf32 -> packed bf16 (RNE)
  unsigned x = __float_as_uint(a), y = __float_as_uint(b);
  unsigned lo = (x + 0x7FFFu + ((x >> 16) & 1u)) >> 16;
  unsigned hi = (y + 0x7FFFu + ((y >> 16) & 1u)) >> 16;
  return lo | (hi << 16);
}
__device__ inline unsigned short pk1(float a) {
  unsigned x = __float_as_uint(a);
  return (unsigned short)((x + 0x7FFFu + ((x >> 16) & 1u)) >> 16);
}

// ---------------- fat A: bucket edges via LDS merge (512 thr, 8192 edges)  ||  prep W1 ----------------

__global__ __launch_bounds__(512) void k_fatA(const int* __restrict__ src,
                                              const int* __restrict__ dst,
                                              const float* __restrict__ w,
                                              int* __restrict__ bcnt,
                                              int* __restrict__ bktK,
                                              i32x2* __restrict__ bktSW,
                                              const float* __restrict__ W1,
                                              unsigned short* __restrict__ w1s) {
  int tid = threadIdx.x;
  if (blockIdx.x >= NCH2) {
    int t = (blockIdx.x - NCH2) * 512 + tid;
    if (t < NFEAT * NHID) {
      int k = t >> 7, c = t & 127;
      int idx = (c * 256 + k) ^ ((c & 7) << 3);
      w1s[idx] = pk1(W1[t]);
    }
    return;
  }
  __shared__ int lcnt[NBKT], loff[NBKT], lcur[NBKT], lbase[NBKT];
  __shared__ int eK[EPB2];      // 32 KB
  __shared__ i32x2 eSW[EPB2];   // 64 KB
  if (tid < NBKT) lcnt[tid] = 0;
  __syncthreads();

  int base_e = blockIdx.x * EPB2;
  int nE = N_EDGES - base_e;
  if (nE > EPB2) nE = EPB2;
  int e0 = base_e + tid * 16;
  int key[16];
  i32x2 sw[16];
  bool full = (tid * 16 + 16 <= nE);
  if (full) {
#pragma unroll
    for (int g = 0; g < 4; g++) {
      i32x4 d4 = __builtin_nontemporal_load((const i32x4*)(dst + e0 + g * 4));
      i32x4 s4 = __builtin_nontemporal_load((const i32x4*)(src + e0 + g * 4));
      f32x4 w4 = __builtin_nontemporal_load((const f32x4*)(w + e0 + g * 4));
      int dd[4] = {d4.x, d4.y, d4.z, d4.w};
      int ss[4] = {s4.x, s4.y, s4.z, s4.w};
      float ww[4] = {w4.x, w4.y, w4.z, w4.w};
#pragma unroll
      for (int i = 0; i < 4; i++) {
        key[g * 4 + i] = dd[i] * 8 + (int)((unsigned)ss[i] / NODES_PER_GROUP);
        sw[g * 4 + i].x = ss[i];
        sw[g * 4 + i].y = __float_as_int(ww[i]);
        atomicAdd(&lcnt[(unsigned)dd[i] / NPB], 1);
      }
    }
  } else {
#pragma unroll
    for (int i = 0; i < 16; i++) {
      int e = tid * 16 + i;
      if (e < nE) {
        int d = dst[base_e + e], s = src[base_e + e];
        float ww = w[base_e + e];
        key[i] = d * 8 + (int)((unsigned)s / NODES_PER_GROUP);
        sw[i].x = s;
        sw[i].y = __float_as_int(ww);
        atomicAdd(&lcnt[(unsigned)d / NPB], 1);
      } else {
        key[i] = -1;
      }
    }
  }
  __syncthreads();
  if (tid < NBKT) loff[tid] = lcnt[tid];
  __syncthreads();
  for (int off = 1; off < NBKT; off <<= 1) {
    int u = (tid < NBKT && tid >= off) ? loff[tid - off] : 0;
    __syncthreads();
    if (tid < NBKT) loff[tid] += u;
    __syncthreads();
  }
  if (tid < NBKT) {
    int excl = loff[tid] - lcnt[tid];
    loff[tid] = excl;
    lcur[tid] = excl;
    lbase[tid] = atomicAdd(&bcnt[tid], lcnt[tid]);
  }
  __syncthreads();
#pragma unroll
  for (int i = 0; i < 16; i++) {
    if (key[i] >= 0) {
      int b = (unsigned)key[i] / KPB;
      int p = atomicAdd(&lcur[b], 1);
      eK[p] = key[i];
      eSW[p] = sw[i];
    }
  }
  __syncthreads();
  int wid = tid >> 6, lane = tid & 63;
  for (int b = wid; b < NBKT; b += 8) {
    int cnt = lcnt[b];
    int l0 = loff[b];
    int gb = lbase[b];
    if (gb + cnt > BCAP2) cnt = BCAP2 - gb;  // overflow guard
    size_t g0 = (size_t)b * BCAP2 + gb;
    for (int i = lane; i < cnt; i += 64) {
      bktK[g0 + i] = eK[l0 + i];
      bktSW[g0 + i] = eSW[l0 + i];
    }
  }
}

// ---------------- GEMM1: h1 = bf16(x) @ bf16(W1) via MFMA, bf16 out ----------------

__global__ __launch_bounds__(256) void k_gemm1(const float* __restrict__ x,
                                               const uint4* __restrict__ w1s,
                                               unsigned* __restrict__ h1u) {
  __shared__ char sB[65536];  // swizzled Bt[128][256] bf16
  int tid = threadIdx.x;
  {
    uint4* dd = (uint4*)sB;
    for (int i = 0; i < 16; i++) dd[tid + i * 256] = w1s[tid + i * 256];
  }
  __syncthreads();

  int lane = tid & 63, wid = tid >> 6;
  int r16 = lane & 15, kgrp = lane >> 4;
  int rowbase = blockIdx.x * 128 + wid * 32;
  int ra0 = min(rowbase + r16, N_NODES - 1);
  int ra1 = min(rowbase + 16 + r16, N_NODES - 1);

  f32x4 acc[2][8];
#pragma unroll
  for (int m = 0; m < 2; m++)
#pragma unroll
    for (int n = 0; n < 8; n++) acc[m][n] = (f32x4){0.f, 0.f, 0.f, 0.f};

  for (int kt8 = 0; kt8 < 8; kt8++) {
    int k0 = kt8 * 32 + kgrp * 8;
    union { uint4 u; short8 s; } a[2];
#pragma unroll
    for (int m = 0; m < 2; m++) {
      const float* ap = x + (size_t)(m ? ra1 : ra0) * NFEAT + k0;
      float4 v0 = *(const float4*)ap;
      float4 v1 = *(const float4*)(ap + 4);
      a[m].u.x = pk2(v0.x, v0.y);
      a[m].u.y = pk2(v0.z, v0.w);
      a[m].u.z = pk2(v1.x, v1.y);
      a[m].u.w = pk2(v1.z, v1.w);
    }
#pragma unroll
    for (int n = 0; n < 8; n++) {
      int c = 16 * n + r16;
      int off = (c * 512 + k0 * 2) ^ ((c & 7) << 4);
      short8 b = *(const short8*)(sB + off);
      acc[0][n] = __builtin_amdgcn_mfma_f32_16x16x32_bf16(a[0].s, b, acc[0][n], 0, 0, 0);
      acc[1][n] = __builtin_amdgcn_mfma_f32_16x16x32_bf16(a[1].s, b, acc[1][n], 0, 0, 0);
    }
  }

#pragma unroll
  for (int m = 0; m < 2; m++) {
    int rb = rowbase + m * 16 + kgrp * 4;
#pragma unroll
    for (int n = 0; n < 8; n++) {
      f32x4 v = acc[m][n];
#pragma unroll
      for (int j = 0; j < 4; j++) {
        float o = __shfl_xor(v[j], 1);
        int row = rb + j;
        if (!(lane & 1) && row < N_NODES)
          h1u[(size_t)row * 64 + 8 * n + (r16 >> 1)] = pk2(v[j], o);
      }
    }
  }
}

// ---------------- k_build: per-bucket hist + scan + LDS-scatter + sequential write ----------------

__global__ __launch_bounds__(1024) void k_build(const int* __restrict__ bcnt,
                                                const int* __restrict__ bktK,
                                                const i32x2* __restrict__ bktSW,
                                                int* __restrict__ rp2,
                                                i32x2* __restrict__ esw) {
  __shared__ int lh[KPB];          // hist -> exclusive scan -> cursor
  __shared__ int partial[1024];
  __shared__ int sc[NBKT];
  __shared__ i32x2 ebuf[BCAP2];    // 105.6 KB edge merge buffer

  int b = blockIdx.x;
  int t = threadIdx.x;
  if (t < NBKT) sc[t] = bcnt[t];
  __syncthreads();
  for (int off = 1; off < NBKT; off <<= 1) {
    int u = (t < NBKT && t >= off) ? sc[t - off] : 0;
    __syncthreads();
    if (t < NBKT) sc[t] += u;
    __syncthreads();
  }
  int base = (b == 0) ? 0 : sc[b - 1];
  int cnt = min(bcnt[b], BCAP2);
  const int* kb = bktK + (size_t)b * BCAP2;
  const i32x2* sb = bktSW + (size_t)b * BCAP2;
  int k0 = b * KPB;

  for (int i = t; i < KPB; i += 1024) lh[i] = 0;
  __syncthreads();
  for (int i = t; i < cnt; i += 1024) atomicAdd(&lh[kb[i] - k0], 1);
  __syncthreads();

  int myoff = t * 7;
  int vals[7];
  int s0 = 0;
#pragma unroll
  for (int q = 0; q < 7; q++) {
    int i = myoff + q;
    int v = (i < KPB) ? lh[i] : 0;
    vals[q] = s0;
    s0 += v;
  }
  partial[t] = s0;
  __syncthreads();
  for (int off = 1; off < 1024; off <<= 1) {
    int u = (t >= off) ? partial[t - off] : 0;
    __syncthreads();
    partial[t] += u;
    __syncthreads();
  }
  int excl_base = partial[t] - s0;
  __syncthreads();
#pragma unroll
  for (int q = 0; q < 7; q++) {
    int i = myoff + q;
    if (i < KPB) {
      int e = excl_base + vals[q];
      int gk = k0 + i;
      if (gk < NKEY) rp2[gk] = base + e;
    }
  }
  __syncthreads();
#pragma unroll
  for (int q = 0; q < 7; q++) {
    int i = myoff + q;
    if (i < KPB) lh[i] = excl_base + vals[q];
  }
  if (b == NBKT - 1 && t == 0) rp2[NKEY] = N_EDGES;
  __syncthreads();

  for (int i = t; i < cnt; i += 1024) {
    int lk = kb[i] - k0;
    int pos = atomicAdd(&lh[lk], 1);
    ebuf[pos] = sb[i];
  }
  __syncthreads();

  i32x2* dstp = esw + base;
  for (int i = t; i < cnt; i += 1024) dstp[i] = ebuf[i];
}

// ---------------- SpMM1 + bias + ReLU + fused GEMM2: one wave per node ----------------
// h = relu(spmm(h1) + b1) kept in f32; h @ W2 computed in-wave via LDS; writes h2 (bf16 u32)

__global__ __launch_bounds__(256) void k_spmm1f(const unsigned* __restrict__ h1u,
                                                const int* __restrict__ rp2,
                                                const i32x2* __restrict__ esw,
                                                const float* __restrict__ bias1,
                                                const float* __restrict__ W2,
                                                unsigned* __restrict__ h2u) {
  __shared__ float w2s[NHID * NCLASS];  // 20 KB, [k][c]
  __shared__ float hrow[4][NHID];       // 2 KB, per-wave h row
  int tid = threadIdx.x;
  {
    float4* d4 = (float4*)w2s;
    const float4* s4 = (const float4*)W2;
    for (int i = tid; i < NHID * NCLASS / 4; i += 256) d4[i] = s4[i];
  }
  __syncthreads();

  int node = (blockIdx.x * 256 + tid) >> 6;
  int lane = tid & 63, wid = tid >> 6;
  if (node >= N_NODES) return;  // never taken (100000 % 4 == 0), kept for safety
  int beg = rp2[node * 8], end = rp2[node * 8 + 8];
  float aL0 = 0.f, aL1 = 0.f, aL2 = 0.f, aL3 = 0.f;
  float aH0 = 0.f, aH1 = 0.f, aH2 = 0.f, aH3 = 0.f;
  int j = beg;
  for (; j + 15 < end; j += 16) {
    i32x2 e[16];
#pragma unroll
    for (int q = 0; q < 16; q++) e[q] = esw[j + q];
    unsigned u[16];
#pragma unroll
    for (int q = 0; q < 16; q++) u[q] = h1u[((unsigned)e[q].x << 6) + lane];
#pragma unroll
    for (int q = 0; q < 16; q += 4) {
      float w0 = __int_as_float(e[q].y), w1 = __int_as_float(e[q + 1].y);
      float w2 = __int_as_float(e[q + 2].y), w3 = __int_as_float(e[q + 3].y);
      aL0 = fmaf(w0, blo(u[q]), aL0);     aH0 = fmaf(w0, bhi(u[q]), aH0);
      aL1 = fmaf(w1, blo(u[q + 1]), aL1); aH1 = fmaf(w1, bhi(u[q + 1]), aH1);
      aL2 = fmaf(w2, blo(u[q + 2]), aL2); aH2 = fmaf(w2, bhi(u[q + 2]), aH2);
      aL3 = fmaf(w3, blo(u[q + 3]), aL3); aH3 = fmaf(w3, bhi(u[q + 3]), aH3);
    }
  }
  for (; j + 7 < end; j += 8) {
    i32x2 e0 = esw[j],     e1 = esw[j + 1], e2 = esw[j + 2], e3 = esw[j + 3];
    i32x2 e4 = esw[j + 4], e5 = esw[j + 5], e6 = esw[j + 6], e7 = esw[j + 7];
    unsigned u0 = h1u[((unsigned)e0.x << 6) + lane];
    unsigned u1 = h1u[((unsigned)e1.x << 6) + lane];
    unsigned u2 = h1u[((unsigned)e2.x << 6) + lane];
    unsigned u3 = h1u[((unsigned)e3.x << 6) + lane];
    unsigned u4 = h1u[((unsigned)e4.x << 6) + lane];
    unsigned u5 = h1u[((unsigned)e5.x << 6) + lane];
    unsigned u6 = h1u[((unsigned)e6.x << 6) + lane];
    unsigned u7 = h1u[((unsigned)e7.x << 6) + lane];
    float w0 = __int_as_float(e0.y), w1 = __int_as_float(e1.y);
    float w2 = __int_as_float(e2.y), w3 = __int_as_float(e3.y);
    float w4 = __int_as_float(e4.y), w5 = __int_as_float(e5.y);
    float w6 = __int_as_float(e6.y), w7 = __int_as_float(e7.y);
    aL0 = fmaf(w0, blo(u0), aL0); aH0 = fmaf(w0, bhi(u0), aH0);
    aL1 = fmaf(w1, blo(u1), aL1); aH1 = fmaf(w1, bhi(u1), aH1);
    aL2 = fmaf(w2, blo(u2), aL2); aH2 = fmaf(w2, bhi(u2), aH2);
    aL3 = fmaf(w3, blo(u3), aL3); aH3 = fmaf(w3, bhi(u3), aH3);
    aL0 = fmaf(w4, blo(u4), aL0); aH0 = fmaf(w4, bhi(u4), aH0);
    aL1 = fmaf(w5, blo(u5), aL1); aH1 = fmaf(w5, bhi(u5), aH1);
    aL2 = fmaf(w6, blo(u6), aL2); aH2 = fmaf(w6, bhi(u6), aH2);
    aL3 = fmaf(w7, blo(u7), aL3); aH3 = fmaf(w7, bhi(u7), aH3);
  }
  for (; j + 3 < end; j += 4) {
    i32x2 e0 = esw[j], e1 = esw[j + 1], e2 = esw[j + 2], e3 = esw[j + 3];
    unsigned u0 = h1u[((unsigned)e0.x << 6) + lane];
    unsigned u1 = h1u[((unsigned)e1.x << 6) + lane];
    unsigned u2 = h1u[((unsigned)e2.x << 6) + lane];
    unsigned u3 = h1u[((unsigned)e3.x << 6) + lane];
    float w0 = __int_as_float(e0.y), w1 = __int_as_float(e1.y);
    float w2 = __int_as_float(e2.y), w3 = __int_as_float(e3.y);
    aL0 = fmaf(w0, blo(u0), aL0); aH0 = fmaf(w0, bhi(u0), aH0);
    aL1 = fmaf(w1, blo(u1), aL1); aH1 = fmaf(w1, bhi(u1), aH1);
    aL2 = fmaf(w2, blo(u2), aL2); aH2 = fmaf(w2, bhi(u2), aH2);
    aL3 = fmaf(w3, blo(u3), aL3); aH3 = fmaf(w3, bhi(u3), aH3);
  }
  for (; j < end; j++) {
    i32x2 e0 = esw[j];
    unsigned u0 = h1u[((unsigned)e0.x << 6) + lane];
    float w0 = __int_as_float(e0.y);
    aL0 = fmaf(w0, blo(u0), aL0); aH0 = fmaf(w0, bhi(u0), aH0);
  }
  float r0 = (aL0 + aL1) + (aL2 + aL3) + bias1[2 * lane];
  float r1 = (aH0 + aH1) + (aH2 + aH3) + bias1[2 * lane + 1];
  // h row (f32, post-ReLU) -> per-wave LDS (same-wave producer/consumer, no barrier)
  hrow[wid][2 * lane] = fmaxf(r0, 0.f);
  hrow[wid][2 * lane + 1] = fmaxf(r1, 0.f);

  // fused gemm2: lane c computes dot(h, W2[:,c]) for c<40
  int c = lane < NCLASS ? lane : NCLASS - 1;
  float acc = 0.f;
#pragma unroll 8
  for (int k = 0; k < NHID; k += 4) {
    float4 h4 = *(const float4*)&hrow[wid][k];
    acc = fmaf(h4.x, w2s[k * NCLASS + c], acc);
    acc = fmaf(h4.y, w2s[(k + 1) * NCLASS + c], acc);
    acc = fmaf(h4.z, w2s[(k + 2) * NCLASS + c], acc);
    acc = fmaf(h4.w, w2s[(k + 3) * NCLASS + c], acc);
  }
  int sl0 = lane < 20 ? 2 * lane : 0;
  float v0 = __shfl(acc, sl0);
  float v1 = __shfl(acc, sl0 + 1);
  if (lane < 20) h2u[(size_t)node * 20 + lane] = pk2(v0, v1);
}

// ---------------- SpMM2 + bias: wave per node, 3-way edge split, x2 unroll ----------------

__global__ __launch_bounds__(256) void k_spmm2(const unsigned* __restrict__ h2u,
                                               const int* __restrict__ rp2,
                                               const i32x2* __restrict__ esw,
                                               const float* __restrict__ b2,
                                               float* __restrict__ out) {
  int node = (blockIdx.x * 256 + threadIdx.x) >> 6;
  int lane = threadIdx.x & 63;
  if (node >= N_NODES) return;
  int beg = rp2[node * 8], end = rp2[node * 8 + 8];
  int g = lane / 20;
  int jj = lane - g * 20;
  float aA0 = 0.f, aB0 = 0.f, aA1 = 0.f, aB1 = 0.f;
  if (g < 3) {
    int e = beg + g;
    for (; e + 3 < end; e += 6) {
      i32x2 p0 = esw[e];
      i32x2 p1 = esw[e + 3];
      unsigned u0 = h2u[(size_t)p0.x * 20 + jj];
      unsigned u1 = h2u[(size_t)p1.x * 20 + jj];
      float w0 = __int_as_float(p0.y), w1 = __int_as_float(p1.y);
      aA0 = fmaf(w0, blo(u0), aA0); aB0 = fmaf(w0, bhi(u0), aB0);
      aA1 = fmaf(w1, blo(u1), aA1); aB1 = fmaf(w1, bhi(u1), aB1);
    }
    if (e < end) {
      i32x2 p0 = esw[e];
      unsigned u0 = h2u[(size_t)p0.x * 20 + jj];
      float w0 = __int_as_float(p0.y);
      aA0 = fmaf(w0, blo(u0), aA0); aB0 = fmaf(w0, bhi(u0), aB0);
    }
  }
  float accA = aA0 + aA1, accB = aB0 + aB1;
  float tA = accA + __shfl(accA, lane + 20) + __shfl(accA, lane + 40);
  float tB = accB + __shfl(accB, lane + 20) + __shfl(accB, lane + 40);
  if (lane < 20) {
    float2 o = make_float2(tA + b2[2 * lane], tB + b2[2 * lane + 1]);
    *(float2*)&out[(size_t)node * NCLASS + 2 * lane] = o;
  }
}

extern "C" void kernel_launch(void* const* d_in, const int* in_sizes, int n_in,
                              void* d_out, int out_size, void* d_ws, size_t ws_size,
                              hipStream_t stream) {
  const float* x = (const float*)d_in[0];
  const int* src_in = (const int*)d_in[1];
  const int* dst_in = (const int*)d_in[2];
  const float* w_in = (const float*)d_in[3];
  const float* W1 = (const float*)d_in[4];
  const float* b1 = (const float*)d_in[5];
  const float* W2 = (const float*)d_in[6];
  const float* b2 = (const float*)d_in[7];
  float* out = (float*)d_out;

  // workspace layout (all chunks 16B-aligned)
  unsigned short* h1b = (unsigned short*)d_ws;                      // 25.6 MB
  unsigned* h2u = (unsigned*)(h1b + (size_t)N_NODES * NHID);        // 8 MB (bf16 pairs)
  i32x2* esw = (i32x2*)(h2u + (size_t)N_NODES * 20);                // 12.8 MB
  i32x2* bktSW = esw + N_EDGES;                                     // 13.52 MB
  int* bktK = (int*)(bktSW + (size_t)NBKT * BCAP2);                 // 6.76 MB
  int* bcnt = bktK + (size_t)NBKT * BCAP2;                          // 128
  int* rp2 = bcnt + NBKT;                                           // 800001 ints (+pad)
  unsigned short* w1s = (unsigned short*)(rp2 + NKEY + 4);          // 64 KB

  hipMemsetAsync(bcnt, 0, NBKT * sizeof(int), stream);
  k_fatA<<<NCH2 + 64, 512, 0, stream>>>(src_in, dst_in, w_in, bcnt, bktK, bktSW, W1, w1s);
  k_gemm1<<<NGEMM1, 256, 0, stream>>>(x, (const uint4*)w1s, (unsigned*)h1b);
  k_build<<<NBKT, 1024, 0, stream>>>(bcnt, bktK, bktSW, rp2, esw);

  k_spmm1f<<<(N_NODES + 3) / 4, 256, 0, stream>>>((const unsigned*)h1b, rp2, esw, b1, W2, h2u);
  k_spmm2<<<(N_NODES + 3) / 4, 256, 0, stream>>>((const unsigned*)h2u, rp2, esw, b2, out);
}

// Round 16
// 224.262 us; speedup vs baseline: 1.1032x; 1.1032x over previous
//
#include <hip/hip_runtime.h>

#define N_NODES 100000
#define N_EDGES 1600000
#define NFEAT 256
#define NHID 128
#define NCLASS 40

#define NGROUP 8               // src ranges (key minor dim)
#define NODES_PER_GROUP 12500
#define NBKT 128               // dst buckets
#define NPB 782                // ceil(N_NODES / NBKT)
#define KPB (NPB * 8)          // 6256 keys per bucket
#define BCAP2 13200            // per-bucket capacity (mean 12500, +6.3 sigma)
#define EPB2 8192              // edges per fatA block (512 thr x 16)
#define NCH2 ((N_EDGES + EPB2 - 1) / EPB2)  // 196
#define NGEMM1 ((N_NODES + 127) / 128)  // 782
#define NKEY (N_NODES * 8)     // 800000 (dst*8 + src_range)

using short8 = __attribute__((ext_vector_type(8))) short;
using f32x4 = __attribute__((ext_vector_type(4))) float;
using i32x4 = __attribute__((ext_vector_type(4))) int;
using i32x2 = __attribute__((ext_vector_type(2))) int;

// ---------- bf16 helpers ----------
__device__ inline float blo(unsigned u) { return __uint_as_float(u << 16); }
__device__ inline float bhi(unsigned u) { return __uint_as_float(u & 0xffff0000u); }
__device__ inline unsigned pk2(float a, float b) {  // 2xf32 -> packed bf16 (RNE)
  unsigned x = __float_as_uint(a), y = __float_as_uint(b);
  unsigned lo = (x + 0x7FFFu + ((x >> 16) & 1u)) >> 16;
  unsigned hi = (y + 0x7FFFu + ((y >> 16) & 1u)) >> 16;
  return lo | (hi << 16);
}
__device__ inline unsigned short pk1(float a) {
  unsigned x = __float_as_uint(a);
  return (unsigned short)((x + 0x7FFFu + ((x >> 16) & 1u)) >> 16);
}

// ---------------- fat A: bucket edges via LDS merge (512 thr, 8192 edges)  ||  prep W1 ----------------

__global__ __launch_bounds__(512) void k_fatA(const int* __restrict__ src,
                                              const int* __restrict__ dst,
                                              const float* __restrict__ w,
                                              int* __restrict__ bcnt,
                                              int* __restrict__ bktK,
                                              i32x2* __restrict__ bktSW,
                                              const float* __restrict__ W1,
                                              unsigned short* __restrict__ w1s) {
  int tid = threadIdx.x;
  if (blockIdx.x >= NCH2) {
    int t = (blockIdx.x - NCH2) * 512 + tid;
    if (t < NFEAT * NHID) {
      int k = t >> 7, c = t & 127;
      int idx = (c * 256 + k) ^ ((c & 7) << 3);
      w1s[idx] = pk1(W1[t]);
    }
    return;
  }
  __shared__ int lcnt[NBKT], loff[NBKT], lcur[NBKT], lbase[NBKT];
  __shared__ int eK[EPB2];      // 32 KB
  __shared__ i32x2 eSW[EPB2];   // 64 KB
  if (tid < NBKT) lcnt[tid] = 0;
  __syncthreads();

  int base_e = blockIdx.x * EPB2;
  int nE = N_EDGES - base_e;
  if (nE > EPB2) nE = EPB2;
  int e0 = base_e + tid * 16;
  int key[16];
  i32x2 sw[16];
  bool full = (tid * 16 + 16 <= nE);
  if (full) {
#pragma unroll
    for (int g = 0; g < 4; g++) {
      i32x4 d4 = __builtin_nontemporal_load((const i32x4*)(dst + e0 + g * 4));
      i32x4 s4 = __builtin_nontemporal_load((const i32x4*)(src + e0 + g * 4));
      f32x4 w4 = __builtin_nontemporal_load((const f32x4*)(w + e0 + g * 4));
      int dd[4] = {d4.x, d4.y, d4.z, d4.w};
      int ss[4] = {s4.x, s4.y, s4.z, s4.w};
      float ww[4] = {w4.x, w4.y, w4.z, w4.w};
#pragma unroll
      for (int i = 0; i < 4; i++) {
        key[g * 4 + i] = dd[i] * 8 + (int)((unsigned)ss[i] / NODES_PER_GROUP);
        sw[g * 4 + i].x = ss[i];
        sw[g * 4 + i].y = __float_as_int(ww[i]);
        atomicAdd(&lcnt[(unsigned)dd[i] / NPB], 1);
      }
    }
  } else {
#pragma unroll
    for (int i = 0; i < 16; i++) {
      int e = tid * 16 + i;
      if (e < nE) {
        int d = dst[base_e + e], s = src[base_e + e];
        float ww = w[base_e + e];
        key[i] = d * 8 + (int)((unsigned)s / NODES_PER_GROUP);
        sw[i].x = s;
        sw[i].y = __float_as_int(ww);
        atomicAdd(&lcnt[(unsigned)d / NPB], 1);
      } else {
        key[i] = -1;
      }
    }
  }
  __syncthreads();
  if (tid < NBKT) loff[tid] = lcnt[tid];
  __syncthreads();
  for (int off = 1; off < NBKT; off <<= 1) {
    int u = (tid < NBKT && tid >= off) ? loff[tid - off] : 0;
    __syncthreads();
    if (tid < NBKT) loff[tid] += u;
    __syncthreads();
  }
  if (tid < NBKT) {
    int excl = loff[tid] - lcnt[tid];
    loff[tid] = excl;
    lcur[tid] = excl;
    lbase[tid] = atomicAdd(&bcnt[tid], lcnt[tid]);
  }
  __syncthreads();
#pragma unroll
  for (int i = 0; i < 16; i++) {
    if (key[i] >= 0) {
      int b = (unsigned)key[i] / KPB;
      int p = atomicAdd(&lcur[b], 1);
      eK[p] = key[i];
      eSW[p] = sw[i];
    }
  }
  __syncthreads();
  int wid = tid >> 6, lane = tid & 63;
  for (int b = wid; b < NBKT; b += 8) {
    int cnt = lcnt[b];
    int l0 = loff[b];
    int gb = lbase[b];
    if (gb + cnt > BCAP2) cnt = BCAP2 - gb;  // overflow guard
    size_t g0 = (size_t)b * BCAP2 + gb;
    for (int i = lane; i < cnt; i += 64) {
      bktK[g0 + i] = eK[l0 + i];
      bktSW[g0 + i] = eSW[l0 + i];
    }
  }
}

// ---------------- GEMM1: h1 = bf16(x) @ bf16(W1) via MFMA, bf16 out ----------------

__global__ __launch_bounds__(256) void k_gemm1(const float* __restrict__ x,
                                               const uint4* __restrict__ w1s,
                                               unsigned* __restrict__ h1u) {
  __shared__ char sB[65536];  // swizzled Bt[128][256] bf16
  int tid = threadIdx.x;
  {
    uint4* dd = (uint4*)sB;
    for (int i = 0; i < 16; i++) dd[tid + i * 256] = w1s[tid + i * 256];
  }
  __syncthreads();

  int lane = tid & 63, wid = tid >> 6;
  int r16 = lane & 15, kgrp = lane >> 4;
  int rowbase = blockIdx.x * 128 + wid * 32;
  int ra0 = min(rowbase + r16, N_NODES - 1);
  int ra1 = min(rowbase + 16 + r16, N_NODES - 1);

  f32x4 acc[2][8];
#pragma unroll
  for (int m = 0; m < 2; m++)
#pragma unroll
    for (int n = 0; n < 8; n++) acc[m][n] = (f32x4){0.f, 0.f, 0.f, 0.f};

  for (int kt8 = 0; kt8 < 8; kt8++) {
    int k0 = kt8 * 32 + kgrp * 8;
    union { uint4 u; short8 s; } a[2];
#pragma unroll
    for (int m = 0; m < 2; m++) {
      const float* ap = x + (size_t)(m ? ra1 : ra0) * NFEAT + k0;
      float4 v0 = *(const float4*)ap;
      float4 v1 = *(const float4*)(ap + 4);
      a[m].u.x = pk2(v0.x, v0.y);
      a[m].u.y = pk2(v0.z, v0.w);
      a[m].u.z = pk2(v1.x, v1.y);
      a[m].u.w = pk2(v1.z, v1.w);
    }
#pragma unroll
    for (int n = 0; n < 8; n++) {
      int c = 16 * n + r16;
      int off = (c * 512 + k0 * 2) ^ ((c & 7) << 4);
      short8 b = *(const short8*)(sB + off);
      acc[0][n] = __builtin_amdgcn_mfma_f32_16x16x32_bf16(a[0].s, b, acc[0][n], 0, 0, 0);
      acc[1][n] = __builtin_amdgcn_mfma_f32_16x16x32_bf16(a[1].s, b, acc[1][n], 0, 0, 0);
    }
  }

#pragma unroll
  for (int m = 0; m < 2; m++) {
    int rb = rowbase + m * 16 + kgrp * 4;
#pragma unroll
    for (int n = 0; n < 8; n++) {
      f32x4 v = acc[m][n];
#pragma unroll
      for (int j = 0; j < 4; j++) {
        float o = __shfl_xor(v[j], 1);
        int row = rb + j;
        if (!(lane & 1) && row < N_NODES)
          h1u[(size_t)row * 64 + 8 * n + (r16 >> 1)] = pk2(v[j], o);
      }
    }
  }
}

// ---------------- k_build: per-bucket hist + scan + LDS-scatter + sequential write ----------------
// (bucket-base scan inlined: each block scans the 128 bcnt values itself)

__global__ __launch_bounds__(1024) void k_build(const int* __restrict__ bcnt,
                                                const int* __restrict__ bktK,
                                                const i32x2* __restrict__ bktSW,
                                                int* __restrict__ rp2,
                                                i32x2* __restrict__ esw) {
  __shared__ int lh[KPB];          // hist -> exclusive scan -> cursor
  __shared__ int partial[1024];
  __shared__ int sc[NBKT];
  __shared__ i32x2 ebuf[BCAP2];    // 105.6 KB edge merge buffer

  int b = blockIdx.x;
  int t = threadIdx.x;
  if (t < NBKT) sc[t] = bcnt[t];
  __syncthreads();
  for (int off = 1; off < NBKT; off <<= 1) {
    int u = (t < NBKT && t >= off) ? sc[t - off] : 0;
    __syncthreads();
    if (t < NBKT) sc[t] += u;
    __syncthreads();
  }
  int base = (b == 0) ? 0 : sc[b - 1];
  int cnt = min(bcnt[b], BCAP2);
  const int* kb = bktK + (size_t)b * BCAP2;
  const i32x2* sb = bktSW + (size_t)b * BCAP2;
  int k0 = b * KPB;

  for (int i = t; i < KPB; i += 1024) lh[i] = 0;
  __syncthreads();
  for (int i = t; i < cnt; i += 1024) atomicAdd(&lh[kb[i] - k0], 1);
  __syncthreads();

  int myoff = t * 7;
  int vals[7];
  int s0 = 0;
#pragma unroll
  for (int q = 0; q < 7; q++) {
    int i = myoff + q;
    int v = (i < KPB) ? lh[i] : 0;
    vals[q] = s0;
    s0 += v;
  }
  partial[t] = s0;
  __syncthreads();
  for (int off = 1; off < 1024; off <<= 1) {
    int u = (t >= off) ? partial[t - off] : 0;
    __syncthreads();
    partial[t] += u;
    __syncthreads();
  }
  int excl_base = partial[t] - s0;
  __syncthreads();
#pragma unroll
  for (int q = 0; q < 7; q++) {
    int i = myoff + q;
    if (i < KPB) {
      int e = excl_base + vals[q];
      int gk = k0 + i;
      if (gk < NKEY) rp2[gk] = base + e;
    }
  }
  __syncthreads();
#pragma unroll
  for (int q = 0; q < 7; q++) {
    int i = myoff + q;
    if (i < KPB) lh[i] = excl_base + vals[q];
  }
  if (b == NBKT - 1 && t == 0) rp2[NKEY] = N_EDGES;
  __syncthreads();

  for (int i = t; i < cnt; i += 1024) {
    int lk = kb[i] - k0;
    int pos = atomicAdd(&lh[lk], 1);
    ebuf[pos] = sb[i];
  }
  __syncthreads();

  i32x2* dstp = esw + base;
  for (int i = t; i < cnt; i += 1024) dstp[i] = ebuf[i];
}

// ---------------- SpMM1 + bias + ReLU: one wave per node, bf16 gather, x16 unroll ----------------

__global__ __launch_bounds__(256) void k_spmm1(const unsigned* __restrict__ h1u,
                                               const int* __restrict__ rp2,
                                               const i32x2* __restrict__ esw,
                                               const float* __restrict__ bias1,
                                               unsigned* __restrict__ houtu) {
  int node = (blockIdx.x * 256 + threadIdx.x) >> 6;
  int lane = threadIdx.x & 63;
  if (node >= N_NODES) return;
  int beg = rp2[node * 8], end = rp2[node * 8 + 8];
  float aL0 = 0.f, aL1 = 0.f, aL2 = 0.f, aL3 = 0.f;
  float aH0 = 0.f, aH1 = 0.f, aH2 = 0.f, aH3 = 0.f;
  int j = beg;
  for (; j + 15 < end; j += 16) {
    i32x2 e[16];
#pragma unroll
    for (int q = 0; q < 16; q++) e[q] = esw[j + q];
    unsigned u[16];
#pragma unroll
    for (int q = 0; q < 16; q++) u[q] = h1u[((unsigned)e[q].x << 6) + lane];
#pragma unroll
    for (int q = 0; q < 16; q += 4) {
      float w0 = __int_as_float(e[q].y), w1 = __int_as_float(e[q + 1].y);
      float w2 = __int_as_float(e[q + 2].y), w3 = __int_as_float(e[q + 3].y);
      aL0 = fmaf(w0, blo(u[q]), aL0);     aH0 = fmaf(w0, bhi(u[q]), aH0);
      aL1 = fmaf(w1, blo(u[q + 1]), aL1); aH1 = fmaf(w1, bhi(u[q + 1]), aH1);
      aL2 = fmaf(w2, blo(u[q + 2]), aL2); aH2 = fmaf(w2, bhi(u[q + 2]), aH2);
      aL3 = fmaf(w3, blo(u[q + 3]), aL3); aH3 = fmaf(w3, bhi(u[q + 3]), aH3);
    }
  }
  for (; j + 7 < end; j += 8) {
    i32x2 e0 = esw[j],     e1 = esw[j + 1], e2 = esw[j + 2], e3 = esw[j + 3];
    i32x2 e4 = esw[j + 4], e5 = esw[j + 5], e6 = esw[j + 6], e7 = esw[j + 7];
    unsigned u0 = h1u[((unsigned)e0.x << 6) + lane];
    unsigned u1 = h1u[((unsigned)e1.x << 6) + lane];
    unsigned u2 = h1u[((unsigned)e2.x << 6) + lane];
    unsigned u3 = h1u[((unsigned)e3.x << 6) + lane];
    unsigned u4 = h1u[((unsigned)e4.x << 6) + lane];
    unsigned u5 = h1u[((unsigned)e5.x << 6) + lane];
    unsigned u6 = h1u[((unsigned)e6.x << 6) + lane];
    unsigned u7 = h1u[((unsigned)e7.x << 6) + lane];
    float w0 = __int_as_float(e0.y), w1 = __int_as_float(e1.y);
    float w2 = __int_as_float(e2.y), w3 = __int_as_float(e3.y);
    float w4 = __int_as_float(e4.y), w5 = __int_as_float(e5.y);
    float w6 = __int_as_float(e6.y), w7 = __int_as_float(e7.y);
    aL0 = fmaf(w0, blo(u0), aL0); aH0 = fmaf(w0, bhi(u0), aH0);
    aL1 = fmaf(w1, blo(u1), aL1); aH1 = fmaf(w1, bhi(u1), aH1);
    aL2 = fmaf(w2, blo(u2), aL2); aH2 = fmaf(w2, bhi(u2), aH2);
    aL3 = fmaf(w3, blo(u3), aL3); aH3 = fmaf(w3, bhi(u3), aH3);
    aL0 = fmaf(w4, blo(u4), aL0); aH0 = fmaf(w4, bhi(u4), aH0);
    aL1 = fmaf(w5, blo(u5), aL1); aH1 = fmaf(w5, bhi(u5), aH1);
    aL2 = fmaf(w6, blo(u6), aL2); aH2 = fmaf(w6, bhi(u6), aH2);
    aL3 = fmaf(w7, blo(u7), aL3); aH3 = fmaf(w7, bhi(u7), aH3);
  }
  for (; j + 3 < end; j += 4) {
    i32x2 e0 = esw[j], e1 = esw[j + 1], e2 = esw[j + 2], e3 = esw[j + 3];
    unsigned u0 = h1u[((unsigned)e0.x << 6) + lane];
    unsigned u1 = h1u[((unsigned)e1.x << 6) + lane];
    unsigned u2 = h1u[((unsigned)e2.x << 6) + lane];
    unsigned u3 = h1u[((unsigned)e3.x << 6) + lane];
    float w0 = __int_as_float(e0.y), w1 = __int_as_float(e1.y);
    float w2 = __int_as_float(e2.y), w3 = __int_as_float(e3.y);
    aL0 = fmaf(w0, blo(u0), aL0); aH0 = fmaf(w0, bhi(u0), aH0);
    aL1 = fmaf(w1, blo(u1), aL1); aH1 = fmaf(w1, bhi(u1), aH1);
    aL2 = fmaf(w2, blo(u2), aL2); aH2 = fmaf(w2, bhi(u2), aH2);
    aL3 = fmaf(w3, blo(u3), aL3); aH3 = fmaf(w3, bhi(u3), aH3);
  }
  for (; j < end; j++) {
    i32x2 e0 = esw[j];
    unsigned u0 = h1u[((unsigned)e0.x << 6) + lane];
    float w0 = __int_as_float(e0.y);
    aL0 = fmaf(w0, blo(u0), aL0); aH0 = fmaf(w0, bhi(u0), aH0);
  }
  float r0 = (aL0 + aL1) + (aL2 + aL3) + bias1[2 * lane];
  float r1 = (aH0 + aH1) + (aH2 + aH3) + bias1[2 * lane + 1];
  houtu[(size_t)node * 64 + lane] = pk2(fmaxf(r0, 0.f), fmaxf(r1, 0.f));
}

// ---------------- GEMM2: h2 = h @ W2  (bf16 in, bf16 out) ----------------

__global__ __launch_bounds__(256) void k_gemm2(const unsigned* __restrict__ h_u,
                                               const float* __restrict__ W2,
                                               unsigned short* __restrict__ h2b) {
  __shared__ float hs[32][132];
  __shared__ float w2t[40][132];
  int tid = threadIdx.x;
  int row0 = blockIdx.x * 32;
  for (int i = tid; i < NHID * NCLASS; i += 256) {
    int k = i / NCLASS, c = i % NCLASS;
    w2t[c][k] = W2[i];
  }
  for (int i = tid; i < 2048; i += 256) {
    int r = i >> 6, c = i & 63;
    unsigned u = h_u[(size_t)(row0 + r) * 64 + c];
    hs[r][2 * c] = blo(u);
    hs[r][2 * c + 1] = bhi(u);
  }
  __syncthreads();
  int r = tid >> 3;
  int c0 = (tid & 7) * 5;
  float acc[5] = {0, 0, 0, 0, 0};
  for (int k = 0; k < NHID; k += 4) {
    float4 a = *(float4*)&hs[r][k];
#pragma unroll
    for (int j = 0; j < 5; j++) {
      float4 b = *(float4*)&w2t[c0 + j][k];
      acc[j] += a.x * b.x + a.y * b.y + a.z * b.z + a.w * b.w;
    }
  }
#pragma unroll
  for (int j = 0; j < 5; j++) h2b[(size_t)(row0 + r) * NCLASS + c0 + j] = pk1(acc[j]);
}

// ---------------- SpMM2 + bias: wave per node, 3-way edge split, x2 unroll ----------------

__global__ __launch_bounds__(256) void k_spmm2(const unsigned* __restrict__ h2u,
                                               const int* __restrict__ rp2,
                                               const i32x2* __restrict__ esw,
                                               const float* __restrict__ b2,
                                               float* __restrict__ out) {
  int node = (blockIdx.x * 256 + threadIdx.x) >> 6;
  int lane = threadIdx.x & 63;
  if (node >= N_NODES) return;
  int beg = rp2[node * 8], end = rp2[node * 8 + 8];
  int g = lane / 20;
  int jj = lane - g * 20;
  float aA0 = 0.f, aB0 = 0.f, aA1 = 0.f, aB1 = 0.f;
  if (g < 3) {
    int e = beg + g;
    for (; e + 3 < end; e += 6) {
      i32x2 p0 = esw[e];
      i32x2 p1 = esw[e + 3];
      unsigned u0 = h2u[(size_t)p0.x * 20 + jj];
      unsigned u1 = h2u[(size_t)p1.x * 20 + jj];
      float w0 = __int_as_float(p0.y), w1 = __int_as_float(p1.y);
      aA0 = fmaf(w0, blo(u0), aA0); aB0 = fmaf(w0, bhi(u0), aB0);
      aA1 = fmaf(w1, blo(u1), aA1); aB1 = fmaf(w1, bhi(u1), aB1);
    }
    if (e < end) {
      i32x2 p0 = esw[e];
      unsigned u0 = h2u[(size_t)p0.x * 20 + jj];
      float w0 = __int_as_float(p0.y);
      aA0 = fmaf(w0, blo(u0), aA0); aB0 = fmaf(w0, bhi(u0), aB0);
    }
  }
  float accA = aA0 + aA1, accB = aB0 + aB1;
  float tA = accA + __shfl(accA, lane + 20) + __shfl(accA, lane + 40);
  float tB = accB + __shfl(accB, lane + 20) + __shfl(accB, lane + 40);
  if (lane < 20) {
    float2 o = make_float2(tA + b2[2 * lane], tB + b2[2 * lane + 1]);
    *(float2*)&out[(size_t)node * NCLASS + 2 * lane] = o;
  }
}

extern "C" void kernel_launch(void* const* d_in, const int* in_sizes, int n_in,
                              void* d_out, int out_size, void* d_ws, size_t ws_size,
                              hipStream_t stream) {
  const float* x = (const float*)d_in[0];
  const int* src_in = (const int*)d_in[1];
  const int* dst_in = (const int*)d_in[2];
  const float* w_in = (const float*)d_in[3];
  const float* W1 = (const float*)d_in[4];
  const float* b1 = (const float*)d_in[5];
  const float* W2 = (const float*)d_in[6];
  const float* b2 = (const float*)d_in[7];
  float* out = (float*)d_out;

  // workspace layout (all chunks 16B-aligned)
  unsigned short* h1b = (unsigned short*)d_ws;                      // 25.6 MB
  unsigned* hbuf = (unsigned*)(h1b + (size_t)N_NODES * NHID);       // 25.6 MB
  unsigned short* h2b = (unsigned short*)(hbuf + (size_t)N_NODES * 64);  // 8 MB
  i32x2* esw = (i32x2*)(h2b + (size_t)N_NODES * NCLASS);            // 12.8 MB
  i32x2* bktSW = esw + N_EDGES;                                     // 13.52 MB
  int* bktK = (int*)(bktSW + (size_t)NBKT * BCAP2);                 // 6.76 MB
  int* bcnt = bktK + (size_t)NBKT * BCAP2;                          // 128
  int* rp2 = bcnt + NBKT;                                           // 800001 ints (+pad)
  unsigned short* w1s = (unsigned short*)(rp2 + NKEY + 4);          // 64 KB

  hipMemsetAsync(bcnt, 0, NBKT * sizeof(int), stream);
  k_fatA<<<NCH2 + 64, 512, 0, stream>>>(src_in, dst_in, w_in, bcnt, bktK, bktSW, W1, w1s);
  k_gemm1<<<NGEMM1, 256, 0, stream>>>(x, (const uint4*)w1s, (unsigned*)h1b);
  k_build<<<NBKT, 1024, 0, stream>>>(bcnt, bktK, bktSW, rp2, esw);

  k_spmm1<<<(N_NODES + 3) / 4, 256, 0, stream>>>((const unsigned*)h1b, rp2, esw, b1, hbuf);
  k_gemm2<<<N_NODES / 32, 256, 0, stream>>>(hbuf, W2, h2b);
  k_spmm2<<<(N_NODES + 3) / 4, 256, 0, stream>>>((const unsigned*)h2b, rp2, esw, b2, out);
}